// Round 9
// baseline (110.993 us; speedup 1.0000x reference)
//
#include <hip/hip_runtime.h>
#include <hip/hip_bf16.h>

// CapsuleLayer dynamic routing, MI355X. fp32 in/out.
// C=10, B=128, N=1152, IN=8, OUT=16, 3 routing iters.
//
// v7 (round 9): r8 + build-loop unroll cap. ONE change.
//   r5/r7/r8 forensics: dur (~50 us), VGPR_Count (68) and Occupancy (17%)
//   were all INSENSITIVE to per-thread P-state size (72 fp32 -> 36 packed).
//   VALUBusy*dur back-solves to ~2048 VALU instr/wave (correct), so waves
//   stall ~6x their issue time with no co-resident wave to cover ->
//   true residency ~1.4 waves/SIMD. Cause: the fully-unrolled 9-pass build
//   loop lets the scheduler hoist up to 9x12 float4 loads -> hundreds of
//   in-flight regs parked in AGPRs (unified file; VGPR_Count hides them)
//   -> ~1 wave/SIMD. Fix: #pragma unroll 2 on the pass loop bounds in-flight
//   loads (~24 loads ~ 96 regs); latency hiding moves to TLP (4-5 waves/SIMD,
//   all 640 blocks co-resident).
//
// Structure (unchanged from r8): G=2, 512 thr, one block per (c, b-pair).
//   Lane l: o-quad q=l&3 (owns o=q*4..+3), row-sub r=l>>2; wave w covers rows
//   [w*144,(w+1)*144) in 9 passes of 16. W float4 load = 16 rows x 64 B fully-
//   consumed lines. P packed bf16x2 (fp32 accum everywhere else).
//   Logit state eliminated: logit = dot(accum-out, P) recomputed per iter.
//   Unnormalized softmax (|logit| <~ 30, fp32-safe).

constexpr int C = 10, B = 128, N = 1152, IN = 8, OUT = 16;
constexpr int THREADS = 512;
constexpr int NW = THREADS / 64;          // 8 waves
constexpr int G = 2;                      // batches per block
constexpr int PASSES = N / (NW * 16);     // 9

__device__ __forceinline__ unsigned packbf(float a, float b) {
    __hip_bfloat162 h = __float22bfloat162_rn(float2{a, b});  // RNE
    return *(unsigned*)&h;
}
__device__ __forceinline__ float bflo(unsigned u) { return __uint_as_float(u << 16); }
__device__ __forceinline__ float bfhi(unsigned u) { return __uint_as_float(u & 0xffff0000u); }

__global__ __launch_bounds__(THREADS)
void caps_route(const float* __restrict__ Xf, const float* __restrict__ Wf,
                float* __restrict__ Of) {
    __shared__ float lds_s[G][NW][OUT];   // per-wave weighted sums
    __shared__ float lds_sum[G][NW];      // per-wave softmax denominators
    __shared__ float lds_out[G][OUT];     // squashed outputs (per iter)

    const int t = threadIdx.x;
    const int l = t & 63;
    const int wid = t >> 6;
    const int q = l & 3;        // o-quad: owns o = q*4 .. q*4+3
    const int rsub = l >> 2;    // row-sub within a pass (0..15)
    const int blk = blockIdx.x;
    const int c = blk >> 6;     // 64 consecutive blocks share c -> W[c] in L2
    const int b0 = (blk & 63) * G;

    // P packed: Pk[g][p][0] = bf16x2(P0,P1), Pk[g][p][1] = bf16x2(P2,P3)
    unsigned Pk[G][PASSES][2];

    // ---- priors: P[n][o] = sum_i x[b,n,i] * W[c,n,i,o] (fp32 acc, bf16 store)
    // UNROLL CAPPED: bounds in-flight loads so the scheduler can't hoist the
    // whole loop's loads into AGPRs (the r5-r8 residency killer).
    #pragma unroll 2
    for (int p = 0; p < PASSES; ++p) {
        const int n = wid * (16 * PASSES) + p * 16 + rsub;
        const float4* wr = (const float4*)(Wf + (size_t)(c * N + n) * (IN * OUT));
        float4 wv[IN];
        #pragma unroll
        for (int i = 0; i < IN; ++i) wv[i] = wr[i * 4 + q];   // 16 full lines/instr
        #pragma unroll
        for (int g = 0; g < G; ++g) {
            const float4* xr = (const float4*)(Xf + (size_t)((b0 + g) * N + n) * IN);
            const float4 xa = xr[0], xc = xr[1];
            const float xs[8] = { xa.x, xa.y, xa.z, xa.w, xc.x, xc.y, xc.z, xc.w };
            float a0 = 0.f, a1 = 0.f, a2 = 0.f, a3 = 0.f;
            #pragma unroll
            for (int i = 0; i < IN; ++i) {
                a0 = fmaf(xs[i], wv[i].x, a0);
                a1 = fmaf(xs[i], wv[i].y, a1);
                a2 = fmaf(xs[i], wv[i].z, a2);
                a3 = fmaf(xs[i], wv[i].w, a3);
            }
            Pk[g][p][0] = packbf(a0, a1);
            Pk[g][p][1] = packbf(a2, a3);
        }
    }

    // accumulated output quad-slice (fp32); logit[p] == dot(oa_full16, P[p])
    float oa[G][4];
    #pragma unroll
    for (int g = 0; g < G; ++g)
        #pragma unroll
        for (int k = 0; k < 4; ++k) oa[g][k] = 0.f;

    // ---- dynamic routing ----
    for (int it = 0; it < 3; ++it) {
        float s4[G][4];
        float ssum[G];
        if (it == 0) {
            // logits all 0 -> e = 1: plain sums
            #pragma unroll
            for (int g = 0; g < G; ++g) {
                ssum[g] = (float)PASSES;
                float a0 = 0.f, a1 = 0.f, a2 = 0.f, a3 = 0.f;
                #pragma unroll
                for (int p = 0; p < PASSES; ++p) {
                    const unsigned u0 = Pk[g][p][0], u1 = Pk[g][p][1];
                    a0 += bflo(u0); a1 += bfhi(u0);
                    a2 += bflo(u1); a3 += bfhi(u1);
                }
                s4[g][0] = a0; s4[g][1] = a1; s4[g][2] = a2; s4[g][3] = a3;
            }
        } else {
            #pragma unroll
            for (int g = 0; g < G; ++g) {
                ssum[g] = 0.f;
                #pragma unroll
                for (int k = 0; k < 4; ++k) s4[g][k] = 0.f;
                #pragma unroll
                for (int p = 0; p < PASSES; ++p) {
                    const unsigned u0 = Pk[g][p][0], u1 = Pk[g][p][1];
                    const float p0 = bflo(u0), p1 = bfhi(u0);
                    const float p2 = bflo(u1), p3 = bfhi(u1);
                    // logit[p] = dot(out_accum, P[p]) via quad butterfly
                    float d = oa[g][0] * p0;
                    d = fmaf(oa[g][1], p1, d);
                    d = fmaf(oa[g][2], p2, d);
                    d = fmaf(oa[g][3], p3, d);
                    d += __shfl_xor(d, 1, 64);
                    d += __shfl_xor(d, 2, 64);
                    const float e = __expf(d);      // replicated across quad
                    ssum[g] += e;
                    s4[g][0] = fmaf(e, p0, s4[g][0]);
                    s4[g][1] = fmaf(e, p1, s4[g][1]);
                    s4[g][2] = fmaf(e, p2, s4[g][2]);
                    s4[g][3] = fmaf(e, p3, s4[g][3]);
                }
            }
        }
        // reduce across the 16 row-subs of the wave (masks 4..32; quad bits
        // 0,1 carry replicas (ssum) / distinct o (s4) -> not summed)
        #pragma unroll
        for (int m = 4; m < 64; m <<= 1) {
            #pragma unroll
            for (int g = 0; g < G; ++g) {
                ssum[g] += __shfl_xor(ssum[g], m, 64);
                #pragma unroll
                for (int k = 0; k < 4; ++k) s4[g][k] += __shfl_xor(s4[g][k], m, 64);
            }
        }
        if (l < 4) {  // lane l == quad q: owns o = l*4..l*4+3
            #pragma unroll
            for (int g = 0; g < G; ++g)
                #pragma unroll
                for (int k = 0; k < 4; ++k) lds_s[g][wid][l * 4 + k] = s4[g][k];
        }
        if (l == 0) {
            #pragma unroll
            for (int g = 0; g < G; ++g) lds_sum[g][wid] = ssum[g];
        }
        __syncthreads();   // A

        // cross-wave combine + squash on t<32 (16-lane group per g)
        if (t < 32) {
            const int g = t >> 4, o = t & 15;
            float so = 0.f, S = 0.f;
            #pragma unroll
            for (int w = 0; w < NW; ++w) { so += lds_s[g][w][o]; S += lds_sum[g][w]; }
            so /= S;                          // s_o = softmax-weighted prior sum
            float r = so * so;                // ||s||^2 via 16-lane butterfly
            r += __shfl_xor(r, 1, 64);
            r += __shfl_xor(r, 2, 64);
            r += __shfl_xor(r, 4, 64);
            r += __shfl_xor(r, 8, 64);
            const float ov = so * (r / ((1.f + r) * sqrtf(r + 1e-8f)));
            if (it == 2) Of[((size_t)c * B + b0 + g) * OUT + o] = ov;
            else         lds_out[g][o] = ov;
        }

        if (it < 2) {
            __syncthreads();   // B
            #pragma unroll
            for (int g = 0; g < G; ++g)
                #pragma unroll
                for (int k = 0; k < 4; ++k) oa[g][k] += lds_out[g][q * 4 + k];
        }
    }
}

extern "C" void kernel_launch(void* const* d_in, const int* in_sizes, int n_in,
                              void* d_out, int out_size, void* d_ws, size_t ws_size,
                              hipStream_t stream) {
    const float* X = (const float*)d_in[0];   // [B,N,IN] fp32
    const float* W = (const float*)d_in[1];   // [C,N,IN,OUT] fp32
    float* O = (float*)d_out;                 // [C,B,OUT] fp32
    hipLaunchKernelGGL(caps_route, dim3(C * (B / G)), dim3(THREADS), 0, stream, X, W, O);
}

// Round 10
// 88.649 us; speedup vs baseline: 1.2520x; 1.2520x over previous
//
#include <hip/hip_runtime.h>
#include <hip/hip_bf16.h>

// CapsuleLayer dynamic routing, MI355X. fp32 in/out.
// C=10, B=128, N=1152, IN=8, OUT=16, 3 routing iters.
//
// v8 (round 10): P lives in LDS (bf16x2), registers hold almost nothing.
//   r5-r9 forensics: register-array P is trapped between two compiler
//   pathologies. Full unroll -> scheduler hoists dozens of float4 W-loads
//   into the unified VGPR/AGPR file (~300 regs in flight, hidden from
//   VGPR_Count) -> 1.4 waves/SIMD resident -> latency-bound 48 us.
//   Partial unroll (r9) -> dynamic index into Pk[] -> array demoted to
//   scratch -> 46 MB of HBM scratch traffic -> 63 us. Fix: P in LDS.
//   73.7 KB/block (G=2, bf16x2) -> 2 blocks/CU (16 waves/CU cap, 50% occ).
//   Thread-private slots only (no barrier; lgkmcnt orders same-thread RAW).
//   ds b64 at 8B lane stride = 2-way bank aliasing = free (m136).
//   Full unroll everywhere is safe again: hoisting up to 128 VGPR is free
//   (LDS is the block limiter), and no array demotion is possible.
//
// Structure: G=2, 512 thr, one block per (c, b-pair), 640 blocks.
//   Lane l: o-quad q=l&3 (owns o=q*4..+3), row-sub r=l>>2; wave w covers rows
//   [w*144,(w+1)*144) in 9 passes of 16. W float4 load = 16 rows x 64 B fully-
//   consumed lines (coalescing minimum). fp32 accumulation everywhere; only
//   P storage is bf16 (absmax 0.0078 vs threshold 0.0172, 2.2x margin).
//   Logit state eliminated: logit = dot(accum-out, P) recomputed per iter.
//   Unnormalized softmax (|logit| <~ 30, fp32-safe).

constexpr int C = 10, B = 128, N = 1152, IN = 8, OUT = 16;
constexpr int THREADS = 512;
constexpr int NW = THREADS / 64;          // 8 waves
constexpr int G = 2;                      // batches per block
constexpr int PASSES = N / (NW * 16);     // 9

__device__ __forceinline__ unsigned packbf(float a, float b) {
    __hip_bfloat162 h = __float22bfloat162_rn(float2{a, b});  // RNE
    return *(unsigned*)&h;
}
__device__ __forceinline__ float bflo(unsigned u) { return __uint_as_float(u << 16); }
__device__ __forceinline__ float bfhi(unsigned u) { return __uint_as_float(u & 0xffff0000u); }

__global__ __launch_bounds__(THREADS)
void caps_route(const float* __restrict__ Xf, const float* __restrict__ Wf,
                float* __restrict__ Of) {
    // P packed: .x = bf16x2(P0,P1), .y = bf16x2(P2,P3); thread-private slots
    __shared__ uint2 ldsP[G * PASSES * THREADS];       // 73,728 B
    __shared__ float lds_s[G][NW][OUT];                // per-wave weighted sums
    __shared__ float lds_sum[G][NW];                   // per-wave softmax denoms
    __shared__ float lds_out[G][OUT];                  // squashed outputs

    const int t = threadIdx.x;
    const int l = t & 63;
    const int wid = t >> 6;
    const int q = l & 3;        // o-quad: owns o = q*4 .. q*4+3
    const int rsub = l >> 2;    // row-sub within a pass (0..15)
    const int blk = blockIdx.x;
    const int c = blk >> 6;     // 64 consecutive blocks share c -> W[c] in L2
    const int b0 = (blk & 63) * G;

    // ---- priors: P[n][o] = sum_i x[b,n,i] * W[c,n,i,o] (fp32 acc, bf16 store)
    #pragma unroll
    for (int p = 0; p < PASSES; ++p) {
        const int n = wid * (16 * PASSES) + p * 16 + rsub;
        const float4* wr = (const float4*)(Wf + (size_t)(c * N + n) * (IN * OUT));
        float4 wv[IN];
        #pragma unroll
        for (int i = 0; i < IN; ++i) wv[i] = wr[i * 4 + q];   // 16 full lines/instr
        #pragma unroll
        for (int g = 0; g < G; ++g) {
            const float4* xr = (const float4*)(Xf + (size_t)((b0 + g) * N + n) * IN);
            const float4 xa = xr[0], xc = xr[1];
            const float xs[8] = { xa.x, xa.y, xa.z, xa.w, xc.x, xc.y, xc.z, xc.w };
            float a0 = 0.f, a1 = 0.f, a2 = 0.f, a3 = 0.f;
            #pragma unroll
            for (int i = 0; i < IN; ++i) {
                a0 = fmaf(xs[i], wv[i].x, a0);
                a1 = fmaf(xs[i], wv[i].y, a1);
                a2 = fmaf(xs[i], wv[i].z, a2);
                a3 = fmaf(xs[i], wv[i].w, a3);
            }
            ldsP[(g * PASSES + p) * THREADS + t] =
                uint2{packbf(a0, a1), packbf(a2, a3)};
        }
    }

    // accumulated output quad-slice (fp32); logit[p] == dot(oa_full16, P[p])
    float oa[G][4];
    #pragma unroll
    for (int g = 0; g < G; ++g)
        #pragma unroll
        for (int k = 0; k < 4; ++k) oa[g][k] = 0.f;

    // ---- dynamic routing ----
    for (int it = 0; it < 3; ++it) {
        float s4[G][4];
        float ssum[G];
        if (it == 0) {
            // logits all 0 -> e = 1: plain sums
            #pragma unroll
            for (int g = 0; g < G; ++g) {
                ssum[g] = (float)PASSES;
                float a0 = 0.f, a1 = 0.f, a2 = 0.f, a3 = 0.f;
                #pragma unroll
                for (int p = 0; p < PASSES; ++p) {
                    const uint2 u = ldsP[(g * PASSES + p) * THREADS + t];
                    a0 += bflo(u.x); a1 += bfhi(u.x);
                    a2 += bflo(u.y); a3 += bfhi(u.y);
                }
                s4[g][0] = a0; s4[g][1] = a1; s4[g][2] = a2; s4[g][3] = a3;
            }
        } else {
            #pragma unroll
            for (int g = 0; g < G; ++g) {
                ssum[g] = 0.f;
                #pragma unroll
                for (int k = 0; k < 4; ++k) s4[g][k] = 0.f;
                #pragma unroll
                for (int p = 0; p < PASSES; ++p) {
                    const uint2 u = ldsP[(g * PASSES + p) * THREADS + t];
                    const float p0 = bflo(u.x), p1 = bfhi(u.x);
                    const float p2 = bflo(u.y), p3 = bfhi(u.y);
                    // logit[p] = dot(out_accum, P[p]) via quad butterfly
                    float d = oa[g][0] * p0;
                    d = fmaf(oa[g][1], p1, d);
                    d = fmaf(oa[g][2], p2, d);
                    d = fmaf(oa[g][3], p3, d);
                    d += __shfl_xor(d, 1, 64);
                    d += __shfl_xor(d, 2, 64);
                    const float e = __expf(d);      // replicated across quad
                    ssum[g] += e;
                    s4[g][0] = fmaf(e, p0, s4[g][0]);
                    s4[g][1] = fmaf(e, p1, s4[g][1]);
                    s4[g][2] = fmaf(e, p2, s4[g][2]);
                    s4[g][3] = fmaf(e, p3, s4[g][3]);
                }
            }
        }
        // reduce across the 16 row-subs of the wave (masks 4..32; quad bits
        // 0,1 carry replicas (ssum) / distinct o (s4) -> not summed)
        #pragma unroll
        for (int m = 4; m < 64; m <<= 1) {
            #pragma unroll
            for (int g = 0; g < G; ++g) {
                ssum[g] += __shfl_xor(ssum[g], m, 64);
                #pragma unroll
                for (int k = 0; k < 4; ++k) s4[g][k] += __shfl_xor(s4[g][k], m, 64);
            }
        }
        if (l < 4) {  // lane l == quad q: owns o = l*4..l*4+3
            #pragma unroll
            for (int g = 0; g < G; ++g)
                #pragma unroll
                for (int k = 0; k < 4; ++k) lds_s[g][wid][l * 4 + k] = s4[g][k];
        }
        if (l == 0) {
            #pragma unroll
            for (int g = 0; g < G; ++g) lds_sum[g][wid] = ssum[g];
        }
        __syncthreads();   // A

        // cross-wave combine + squash on t<32 (16-lane group per g)
        if (t < 32) {
            const int g = t >> 4, o = t & 15;
            float so = 0.f, S = 0.f;
            #pragma unroll
            for (int w = 0; w < NW; ++w) { so += lds_s[g][w][o]; S += lds_sum[g][w]; }
            so /= S;                          // s_o = softmax-weighted prior sum
            float r = so * so;                // ||s||^2 via 16-lane butterfly
            r += __shfl_xor(r, 1, 64);
            r += __shfl_xor(r, 2, 64);
            r += __shfl_xor(r, 4, 64);
            r += __shfl_xor(r, 8, 64);
            const float ov = so * (r / ((1.f + r) * sqrtf(r + 1e-8f)));
            if (it == 2) Of[((size_t)c * B + b0 + g) * OUT + o] = ov;
            else         lds_out[g][o] = ov;
        }

        if (it < 2) {
            __syncthreads();   // B
            #pragma unroll
            for (int g = 0; g < G; ++g)
                #pragma unroll
                for (int k = 0; k < 4; ++k) oa[g][k] += lds_out[g][q * 4 + k];
        }
    }
}

extern "C" void kernel_launch(void* const* d_in, const int* in_sizes, int n_in,
                              void* d_out, int out_size, void* d_ws, size_t ws_size,
                              hipStream_t stream) {
    const float* X = (const float*)d_in[0];   // [B,N,IN] fp32
    const float* W = (const float*)d_in[1];   // [C,N,IN,OUT] fp32
    float* O = (float*)d_out;                 // [C,B,OUT] fp32
    hipLaunchKernelGGL(caps_route, dim3(C * (B / G)), dim3(THREADS), 0, stream, X, W, O);
}